// Round 10
// baseline (50.882 us; speedup 1.0000x reference)
//
#include <hip/hip_runtime.h>
#include <hip/hip_bf16.h>
#include <hip/hip_fp8.h>

// AlignConLoss: loss = sum_j [ log(sum_i exp(cn_i . an_j)) - cn_j . an_j ]
// B = 8192, D = 256, fp32 inputs, scalar fp32 out. sim in [-1,1] -> no max.
//
// R9 -> R10: gemm switched to MX-scaled fp8 (mfma_scale_f32_16x16x128_f8f6f4,
// scales = 1.0 = e8m0 byte 127) -> 2x MFMA rate vs non-scaled fp8 (m148).
// K=128/instr spans the whole staging tile, so the K-loop collapses:
// single-shot full-K stage (128 rows x 256 B per matrix, 64 KB LDS),
// one vmcnt(0)+barrier, then 32 MFMA/wave with no further sync.
// Swizzle: phys 16B-slot = logical ^ (row&7), same involution on stage
// source and ds_read (rule #21). A/B packed identically -> any within-lane
// K permutation cancels in the dot product.

#define BROWS 8192
#define DIM   256

typedef int   i32x4 __attribute__((ext_vector_type(4)));
typedef int   i32x8 __attribute__((ext_vector_type(8)));
typedef float f32x4 __attribute__((ext_vector_type(4)));

__device__ __forceinline__ void gload_lds16(const void* g, void* l) {
  __builtin_amdgcn_global_load_lds(
      (const __attribute__((address_space(1))) unsigned int*)g,
      (__attribute__((address_space(3))) unsigned int*)l, 16, 0, 0);
}

__device__ __forceinline__ unsigned char to_e4m3(float v) {
  __hip_fp8_e4m3 t(v);
  return *reinterpret_cast<unsigned char*>(&t);
}

// ---------------------------------------------------------------------------
// Kernel 1: per-row L2 norms -> fp8 e4m3 normalized An/Cn; exact fp32 diag.
// One wave per row. Blocks 0..31 also zero colsum[8192].
// ---------------------------------------------------------------------------
__global__ __launch_bounds__(256) void prep_kernel(
    const float* __restrict__ E1, const float* __restrict__ E2,
    unsigned char* __restrict__ An8, unsigned char* __restrict__ Cn8,
    float* __restrict__ diag, float* __restrict__ colsum) {
  if (blockIdx.x < 32) colsum[blockIdx.x * 256 + threadIdx.x] = 0.f;

  const int w    = threadIdx.x >> 6;
  const int lane = threadIdx.x & 63;
  const int row  = blockIdx.x * 4 + w;
  const size_t base = (size_t)row * DIM + lane * 4;

  const float4 a = *(const float4*)(E1 + base);
  const float4 c = *(const float4*)(E2 + base);

  float sa  = a.x*a.x + a.y*a.y + a.z*a.z + a.w*a.w;
  float sc  = c.x*c.x + c.y*c.y + c.z*c.z + c.w*c.w;
  float sac = a.x*c.x + a.y*c.y + a.z*c.z + a.w*c.w;
#pragma unroll
  for (int o = 32; o > 0; o >>= 1) {
    sa  += __shfl_down(sa,  o);
    sc  += __shfl_down(sc,  o);
    sac += __shfl_down(sac, o);
  }
  const float inva = 1.0f / fmaxf(sqrtf(__shfl(sa, 0)), 1e-8f);
  const float invc = 1.0f / fmaxf(sqrtf(__shfl(sc, 0)), 1e-8f);

  uchar4 pa, pc;
  pa.x = to_e4m3(a.x * inva); pa.y = to_e4m3(a.y * inva);
  pa.z = to_e4m3(a.z * inva); pa.w = to_e4m3(a.w * inva);
  pc.x = to_e4m3(c.x * invc); pc.y = to_e4m3(c.y * invc);
  pc.z = to_e4m3(c.z * invc); pc.w = to_e4m3(c.w * invc);
  *(uchar4*)(An8 + base) = pa;
  *(uchar4*)(Cn8 + base) = pc;
  if (lane == 0) diag[row] = sac * inva * invc;
}

// ---------------------------------------------------------------------------
// Kernel 2: 128x128 sim tile, MX-fp8 mfma_scale 16x16x128 (scale = 1.0).
// Full-K single-shot stage: round j, thread tid writes LDS slot j*256+tid
// (16B), i.e. row j*16+(tid>>4), phys slot tid&15; global source logical
// slot (tid&15)^((tid>>4)&7)  [involution phys = log ^ (row&7)].
// Read: row r, logical slot p = W*8+q*2+{0,1} at phys p^(r&7); the XOR
// spreads each 16-lane q-group over all 8 slot classes -> conflict-free.
// Epilogue: exp + column reduce, one atomicAdd per column per block.
// ---------------------------------------------------------------------------
__global__ __launch_bounds__(256, 2) void gemm_colsum_kernel(
    const unsigned char* __restrict__ Cn8,   // contrast rows -> sim rows i
    const unsigned char* __restrict__ An8,   // anchor rows   -> sim cols j
    float* __restrict__ colsum) {
  __shared__ __align__(16) unsigned char ldsC[128 * 256];  // [row][256 B]
  __shared__ __align__(16) unsigned char ldsA[128 * 256];
  __shared__ float ldscol[2][128];

  const int tid  = threadIdx.x;
  const int lane = tid & 63;
  const int w    = tid >> 6;      // 4 waves
  const int wr   = w >> 1;        // wave row (i) 0..1 -> 64 rows
  const int wc   = w & 1;         // wave col (j) 0..1 -> 64 cols

  const int jtile = blockIdx.x & 63;   // consecutive blocks share itile (L2)
  const int itile = blockIdx.x >> 6;
  const int i0 = itile * 128;
  const int j0 = jtile * 128;

  // staging source (per-lane); round j covers rows j*16 + (tid>>4)
  const int sr = tid >> 4;                   // row-within-round 0..15
  const int pl = (tid & 15) ^ (sr & 7);      // logical 16B slot (inverse swz)
  const unsigned char* gC = Cn8 + (size_t)(i0 + sr) * DIM + pl * 16;
  const unsigned char* gA = An8 + (size_t)(j0 + sr) * DIM + pl * 16;

#pragma unroll
  for (int j = 0; j < 8; ++j) {              // 8 rounds x 16 rows, both mats
    gload_lds16(gC + (size_t)j * 16 * DIM, &ldsC[0] + j * 4096 + w * 1024);
    gload_lds16(gA + (size_t)j * 16 * DIM, &ldsA[0] + j * 4096 + w * 1024);
  }
  asm volatile("s_waitcnt vmcnt(0)" ::: "memory");
  __builtin_amdgcn_sched_barrier(0);
  __builtin_amdgcn_s_barrier();              // full K-panels visible

  f32x4 acc[4][4] = {};
  const int q  = lane >> 4;                  // K-quarter within a window
  const int rb = lane & 15;
  const int SC = 0x7F7F7F7F;                 // e8m0 127 -> scale 1.0

#pragma unroll
  for (int W = 0; W < 2; ++W) {              // two K=128 windows
    i32x8 af[4], bfv[4];
#pragma unroll
    for (int m = 0; m < 4; ++m) {
      const int r  = wr * 64 + m * 16 + rb;
      const int s0 = (W * 8 + q * 2)     ^ (r & 7);
      const int s1 = (W * 8 + q * 2 + 1) ^ (r & 7);
      union { i32x4 h[2]; i32x8 v; } u;
      u.h[0] = *(const i32x4*)(&ldsC[0] + r * 256 + s0 * 16);
      u.h[1] = *(const i32x4*)(&ldsC[0] + r * 256 + s1 * 16);
      af[m] = u.v;
    }
#pragma unroll
    for (int n = 0; n < 4; ++n) {
      const int r  = wc * 64 + n * 16 + rb;
      const int s0 = (W * 8 + q * 2)     ^ (r & 7);
      const int s1 = (W * 8 + q * 2 + 1) ^ (r & 7);
      union { i32x4 h[2]; i32x8 v; } u;
      u.h[0] = *(const i32x4*)(&ldsA[0] + r * 256 + s0 * 16);
      u.h[1] = *(const i32x4*)(&ldsA[0] + r * 256 + s1 * 16);
      bfv[n] = u.v;
    }
    __builtin_amdgcn_s_setprio(1);
#pragma unroll
    for (int m = 0; m < 4; ++m)
#pragma unroll
      for (int n = 0; n < 4; ++n)
        acc[m][n] = __builtin_amdgcn_mfma_scale_f32_16x16x128_f8f6f4(
            af[m], bfv[n], acc[m][n], 0 /*fp8 A*/, 0 /*fp8 B*/,
            0, SC, 0, SC);
    __builtin_amdgcn_s_setprio(0);
  }

  // Epilogue: colpart[j] = sum over this block's 128 i-rows of exp(sim).
  // C/D layout (m89; shape-determined m121): col = lane&15, row=(lane>>4)*4+reg.
#pragma unroll
  for (int n = 0; n < 4; ++n) {
    float s = 0.f;
#pragma unroll
    for (int m = 0; m < 4; ++m) {
      const f32x4 v = acc[m][n];
      s += __expf(v[0]) + __expf(v[1]) + __expf(v[2]) + __expf(v[3]);
    }
    s += __shfl_xor(s, 16);
    s += __shfl_xor(s, 32);
    if (lane < 16) ldscol[wr][wc * 64 + n * 16 + lane] = s;
  }
  __syncthreads();
  if (tid < 128) {
    const float v = ldscol[0][tid] + ldscol[1][tid];
    atomicAdd(&colsum[j0 + tid], v);
  }
}

// ---------------------------------------------------------------------------
// Kernel 3: loss = sum_j log(colsum[j]) - diag[j].  Single block.
// ---------------------------------------------------------------------------
__global__ __launch_bounds__(256) void finalize_kernel(
    const float* __restrict__ colsum, const float* __restrict__ diag,
    float* __restrict__ out) {
  const int t = threadIdx.x;
  float s = 0.f;
  for (int j = t; j < BROWS; j += 256) s += logf(colsum[j]) - diag[j];
#pragma unroll
  for (int o = 32; o > 0; o >>= 1) s += __shfl_down(s, o);
  __shared__ float red[4];
  if ((t & 63) == 0) red[t >> 6] = s;
  __syncthreads();
  if (t == 0) out[0] = red[0] + red[1] + red[2] + red[3];
}

// ---------------------------------------------------------------------------
// ws layout (~4.07 MB):
//   [0, 2MiB)            Cn8 fp8 [8192*256]
//   [2MiB, 4MiB)         An8 fp8 [8192*256]
//   [4MiB, +32KiB)       colsum f32 [8192]
//   [4MiB+32K, +32KiB)   diag   f32 [8192]
// ---------------------------------------------------------------------------
extern "C" void kernel_launch(void* const* d_in, const int* in_sizes, int n_in,
                              void* d_out, int out_size, void* d_ws, size_t ws_size,
                              hipStream_t stream) {
  const float* E1 = (const float*)d_in[0];   // encoder_embedding1 -> anchors
  const float* E2 = (const float*)d_in[1];   // encoder_embedding2 -> contrast
  char* ws = (char*)d_ws;
  unsigned char* Cn8 = (unsigned char*)(ws);
  unsigned char* An8 = (unsigned char*)(ws + (size_t)2 * 1024 * 1024);
  float* colsum = (float*)(ws + (size_t)4 * 1024 * 1024);
  float* diag   = (float*)(ws + (size_t)4 * 1024 * 1024 + 32 * 1024);
  float* out = (float*)d_out;

  prep_kernel<<<BROWS / 4, 256, 0, stream>>>(E1, E2, An8, Cn8, diag, colsum);
  gemm_colsum_kernel<<<(BROWS / 128) * (BROWS / 128), 256, 0, stream>>>(Cn8, An8, colsum);
  finalize_kernel<<<1, 256, 0, stream>>>(colsum, diag, out);
}

// Round 11
// 46.147 us; speedup vs baseline: 1.1026x; 1.1026x over previous
//
#include <hip/hip_runtime.h>
#include <hip/hip_bf16.h>
#include <hip/hip_fp8.h>

// AlignConLoss: loss = sum_j [ log(sum_i exp(cn_i . an_j)) - cn_j . an_j ]
// B = 8192, D = 256, fp32 inputs, scalar fp32 out. sim in [-1,1] -> no max.
//
// R10 -> R11: gemm restructured for pipeline depth (R9/R10 showed it is
// stall-bound, not MFMA- or BW-bound). Each block: stage 128-row C-panel once,
// capture its fragments to 64 VGPRs, then loop 8 j-tiles (64 cols), A-panels
// (16 KB) double-buffered with exact counted-vmcnt (8-deep pipeline).
// MX-fp8 mfma_scale 16x16x128, scales = 1.0. Swizzle identical to R10
// (phys 16B slot = logical ^ (row&7), both sides).

#define BROWS 8192
#define DIM   256

typedef int   i32x4 __attribute__((ext_vector_type(4)));
typedef int   i32x8 __attribute__((ext_vector_type(8)));
typedef float f32x4 __attribute__((ext_vector_type(4)));

__device__ __forceinline__ void gload_lds16(const void* g, void* l) {
  __builtin_amdgcn_global_load_lds(
      (const __attribute__((address_space(1))) unsigned int*)g,
      (__attribute__((address_space(3))) unsigned int*)l, 16, 0, 0);
}

__device__ __forceinline__ unsigned char to_e4m3(float v) {
  __hip_fp8_e4m3 t(v);
  return *reinterpret_cast<unsigned char*>(&t);
}

// ---------------------------------------------------------------------------
// Kernel 1: per-row L2 norms -> fp8 e4m3 normalized An/Cn; exact fp32 diag.
// One wave per row. Blocks 0..31 also zero colsum[8192].
// ---------------------------------------------------------------------------
__global__ __launch_bounds__(256) void prep_kernel(
    const float* __restrict__ E1, const float* __restrict__ E2,
    unsigned char* __restrict__ An8, unsigned char* __restrict__ Cn8,
    float* __restrict__ diag, float* __restrict__ colsum) {
  if (blockIdx.x < 32) colsum[blockIdx.x * 256 + threadIdx.x] = 0.f;

  const int w    = threadIdx.x >> 6;
  const int lane = threadIdx.x & 63;
  const int row  = blockIdx.x * 4 + w;
  const size_t base = (size_t)row * DIM + lane * 4;

  const float4 a = *(const float4*)(E1 + base);
  const float4 c = *(const float4*)(E2 + base);

  float sa  = a.x*a.x + a.y*a.y + a.z*a.z + a.w*a.w;
  float sc  = c.x*c.x + c.y*c.y + c.z*c.z + c.w*c.w;
  float sac = a.x*c.x + a.y*c.y + a.z*c.z + a.w*c.w;
#pragma unroll
  for (int o = 32; o > 0; o >>= 1) {
    sa  += __shfl_down(sa,  o);
    sc  += __shfl_down(sc,  o);
    sac += __shfl_down(sac, o);
  }
  const float inva = 1.0f / fmaxf(sqrtf(__shfl(sa, 0)), 1e-8f);
  const float invc = 1.0f / fmaxf(sqrtf(__shfl(sc, 0)), 1e-8f);

  uchar4 pa, pc;
  pa.x = to_e4m3(a.x * inva); pa.y = to_e4m3(a.y * inva);
  pa.z = to_e4m3(a.z * inva); pa.w = to_e4m3(a.w * inva);
  pc.x = to_e4m3(c.x * invc); pc.y = to_e4m3(c.y * invc);
  pc.z = to_e4m3(c.z * invc); pc.w = to_e4m3(c.w * invc);
  *(uchar4*)(An8 + base) = pa;
  *(uchar4*)(Cn8 + base) = pc;
  if (lane == 0) diag[row] = sac * inva * invc;
}

// ---------------------------------------------------------------------------
// Kernel 2: block = 128 i-rows x 512 j-cols (8 jtiles of 64), MX-fp8
// mfma_scale 16x16x128 (scale=1.0). Grid = 64 itiles x 16 jgroups = 1024.
// C-panel (32 KB) staged once, fragments held in 64 VGPR. A-panels (16 KB)
// double-buffered, counted-vmcnt pipeline 8 deep. 4 waves: (wr,wc) 2x2,
// wave = 64i x 32j per jtile. LDS 64 KB -> 2 blocks/CU.
// vmcnt budget per iter (in-order side-effecting ops, s_barrier-anchored):
//   entry j needs A(j) landed; outstanding after = {j0:A1=4, j1:A2+at0=6,
//   j2-6: at(j-2)+A(j+1)+at(j-1)=8, j7: at5+at6=4}.
// Epilogue per jtile: exp + shfl_xor(16,32) col-reduce, 2 atomics/wave.
// ---------------------------------------------------------------------------
__global__ __launch_bounds__(256, 2) void gemm_colsum_kernel(
    const unsigned char* __restrict__ Cn8,   // contrast rows -> sim rows i
    const unsigned char* __restrict__ An8,   // anchor rows   -> sim cols j
    float* __restrict__ colsum) {
  __shared__ __align__(16) unsigned char ldsC[32768];      // [128 rows][256 B]
  __shared__ __align__(16) unsigned char ldsA[2][16384];   // [buf][64 r][256 B]

  const int tid  = threadIdx.x;
  const int lane = tid & 63;
  const int w    = tid >> 6;      // 4 waves
  const int wr   = w >> 1;        // i-half: 64 rows
  const int wc   = w & 1;         // j-half within a 64-col jtile: 32 cols

  const int jgroup = blockIdx.x & 15;
  const int itile  = blockIdx.x >> 4;
  const int i0 = itile * 128;
  const int j0 = jgroup * 512;

  // staging geometry (per 16-row round): row sr, phys slot tid&15 holds
  // logical slot pl = (tid&15) ^ (sr&7).
  const int sr = tid >> 4;
  const int pl = (tid & 15) ^ (sr & 7);
  const unsigned char* gC = Cn8 + (size_t)(i0 + sr) * DIM + pl * 16;
  const unsigned char* gA = An8 + (size_t)(j0 + sr) * DIM + pl * 16;

  auto stageA = [&](int jj, int buf) {     // 16 KB: 4 rounds x 16 rows
#pragma unroll
    for (int r = 0; r < 4; ++r)
      gload_lds16(gA + (size_t)(jj * 64 + r * 16) * DIM,
                  &ldsA[buf][0] + r * 4096 + w * 1024);
  };

#pragma unroll
  for (int r = 0; r < 8; ++r)              // C-panel: 8 rounds x 16 rows
    gload_lds16(gC + (size_t)(r * 16) * DIM, &ldsC[0] + r * 4096 + w * 1024);
  stageA(0, 0);
  stageA(1, 1);

  asm volatile("s_waitcnt vmcnt(8)" ::: "memory");   // C landed; A0,A1 fly
  __builtin_amdgcn_sched_barrier(0);
  __builtin_amdgcn_s_barrier();

  const int q  = lane >> 4;
  const int rb = lane & 15;
  const int SC = 0x7F7F7F7F;               // e8m0 127 -> scale 1.0

  i32x8 af[4][2];                          // C-panel fragments, held in regs
#pragma unroll
  for (int m = 0; m < 4; ++m) {
    const int r = wr * 64 + m * 16 + rb;
#pragma unroll
    for (int W = 0; W < 2; ++W) {
      const int s0 = (W * 8 + q * 2)     ^ (r & 7);
      const int s1 = (W * 8 + q * 2 + 1) ^ (r & 7);
      union { i32x4 h[2]; i32x8 v; } u;
      u.h[0] = *(const i32x4*)(&ldsC[0] + r * 256 + s0 * 16);
      u.h[1] = *(const i32x4*)(&ldsC[0] + r * 256 + s1 * 16);
      af[m][W] = u.v;
    }
  }
  asm volatile("s_waitcnt lgkmcnt(0)" ::: "memory");
  __builtin_amdgcn_sched_barrier(0);

#pragma unroll
  for (int jj = 0; jj < 8; ++jj) {
    const int b = jj & 1;
    if (jj == 0)      asm volatile("s_waitcnt vmcnt(4)" ::: "memory");
    else if (jj == 1) asm volatile("s_waitcnt vmcnt(6)" ::: "memory");
    else if (jj == 7) asm volatile("s_waitcnt vmcnt(4)" ::: "memory");
    else              asm volatile("s_waitcnt vmcnt(8)" ::: "memory");
    __builtin_amdgcn_sched_barrier(0);
    __builtin_amdgcn_s_barrier();          // A(jj) visible to all waves

    i32x8 bf[2][2];                        // capture full A-tile to regs
#pragma unroll
    for (int n = 0; n < 2; ++n) {
      const int r = wc * 32 + n * 16 + rb;
#pragma unroll
      for (int W = 0; W < 2; ++W) {
        const int s0 = (W * 8 + q * 2)     ^ (r & 7);
        const int s1 = (W * 8 + q * 2 + 1) ^ (r & 7);
        union { i32x4 h[2]; i32x8 v; } u;
        u.h[0] = *(const i32x4*)(&ldsA[b][0] + r * 256 + s0 * 16);
        u.h[1] = *(const i32x4*)(&ldsA[b][0] + r * 256 + s1 * 16);
        bf[n][W] = u.v;
      }
    }
    asm volatile("s_waitcnt lgkmcnt(0)" ::: "memory");
    __builtin_amdgcn_sched_barrier(0);     // rule #18
    __builtin_amdgcn_s_barrier();          // buf b fully consumed
    __builtin_amdgcn_sched_barrier(0);

    if (jj < 6) stageA(jj + 2, b);         // prefetch 2 ahead into freed buf
    __builtin_amdgcn_sched_barrier(0);

    f32x4 acc[4][2] = {};
    __builtin_amdgcn_s_setprio(1);
#pragma unroll
    for (int m = 0; m < 4; ++m)
#pragma unroll
      for (int n = 0; n < 2; ++n)
#pragma unroll
        for (int W = 0; W < 2; ++W)
          acc[m][n] = __builtin_amdgcn_mfma_scale_f32_16x16x128_f8f6f4(
              af[m][W], bf[n][W], acc[m][n], 0, 0, 0, SC, 0, SC);
    __builtin_amdgcn_s_setprio(0);
    __builtin_amdgcn_sched_barrier(0);

    // Epilogue: col partials over this wave's 64 i-rows; C/D layout:
    // col = lane&15, row = (lane>>4)*4 + reg (m89/m121).
#pragma unroll
    for (int n = 0; n < 2; ++n) {
      float s = 0.f;
#pragma unroll
      for (int m = 0; m < 4; ++m) {
        const f32x4 v = acc[m][n];
        s += __expf(v[0]) + __expf(v[1]) + __expf(v[2]) + __expf(v[3]);
      }
      s += __shfl_xor(s, 16);
      s += __shfl_xor(s, 32);
      if (lane < 16)
        atomicAdd(&colsum[j0 + jj * 64 + wc * 32 + n * 16 + lane], s);
    }
    __builtin_amdgcn_sched_barrier(0);
  }
}

// ---------------------------------------------------------------------------
// Kernel 3: loss = sum_j log(colsum[j]) - diag[j].  Single block.
// ---------------------------------------------------------------------------
__global__ __launch_bounds__(256) void finalize_kernel(
    const float* __restrict__ colsum, const float* __restrict__ diag,
    float* __restrict__ out) {
  const int t = threadIdx.x;
  float s = 0.f;
  for (int j = t; j < BROWS; j += 256) s += logf(colsum[j]) - diag[j];
#pragma unroll
  for (int o = 32; o > 0; o >>= 1) s += __shfl_down(s, o);
  __shared__ float red[4];
  if ((t & 63) == 0) red[t >> 6] = s;
  __syncthreads();
  if (t == 0) out[0] = red[0] + red[1] + red[2] + red[3];
}

// ---------------------------------------------------------------------------
// ws layout (~4.07 MB):
//   [0, 2MiB)            Cn8 fp8 [8192*256]
//   [2MiB, 4MiB)         An8 fp8 [8192*256]
//   [4MiB, +32KiB)       colsum f32 [8192]
//   [4MiB+32K, +32KiB)   diag   f32 [8192]
// ---------------------------------------------------------------------------
extern "C" void kernel_launch(void* const* d_in, const int* in_sizes, int n_in,
                              void* d_out, int out_size, void* d_ws, size_t ws_size,
                              hipStream_t stream) {
  const float* E1 = (const float*)d_in[0];   // encoder_embedding1 -> anchors
  const float* E2 = (const float*)d_in[1];   // encoder_embedding2 -> contrast
  char* ws = (char*)d_ws;
  unsigned char* Cn8 = (unsigned char*)(ws);
  unsigned char* An8 = (unsigned char*)(ws + (size_t)2 * 1024 * 1024);
  float* colsum = (float*)(ws + (size_t)4 * 1024 * 1024);
  float* diag   = (float*)(ws + (size_t)4 * 1024 * 1024 + 32 * 1024);
  float* out = (float*)d_out;

  prep_kernel<<<BROWS / 4, 256, 0, stream>>>(E1, E2, An8, Cn8, diag, colsum);
  gemm_colsum_kernel<<<64 * 16, 256, 0, stream>>>(Cn8, An8, colsum);
  finalize_kernel<<<1, 256, 0, stream>>>(colsum, diag, out);
}